// Round 3
// baseline (75.331 us; speedup 1.0000x reference)
//
#include <hip/hip_runtime.h>
#include <math.h>

#define LEN       16384
#define NTHREADS  1024
#define SEG       16          // LEN / NTHREADS
#define NWAVES    16

// exp(-1/20) and derived constants (double-precision values)
#define DECAY_F 0.951229424500714f      // d = exp(-0.05)
#define D16_F   0.449328964117222f      // d^16 = exp(-0.8)
#define G16_F   7.5886329f              // sum_{i=1..16} d^(2i)

// one scan step: s = d*s + x; A += s^2; Bc += d^(i+1)*s  (w constant-folds)
#define STEP(xv) { s = __builtin_fmaf(DECAY_F, s, (xv)); w *= DECAY_F; \
                   A = __builtin_fmaf(s, s, A); Bc = __builtin_fmaf(w, s, Bc); }

__global__ __launch_bounds__(NTHREADS) void vr_fused(
    const float* __restrict__ in, const float* __restrict__ tgt,
    float* __restrict__ partial, unsigned int* __restrict__ counter,
    float* __restrict__ out, int nrows)
{
    __shared__ float wa[NWAVES], wb[NWAVES], red[NWAVES];
    __shared__ int lastdone;

    const int row = blockIdx.x;
    const int tid = threadIdx.x;
    const long long rb = (long long)row * LEN + (long long)tid * SEG;
    const float4* __restrict__ in4 = (const float4*)(in  + rb);
    const float4* __restrict__ tg4 = (const float4*)(tgt + rb);

    // ---- direct global->register: 8 independent float4 loads (high MLP) ----
    const float4 a0 = in4[0], a1 = in4[1], a2 = in4[2], a3 = in4[3];
    const float4 b0 = tg4[0], b1 = tg4[1], b2 = tg4[2], b3 = tg4[3];

    // ---- per-thread local scan + moments, all in registers ----
    // s_i: scan from zero carry. True y_i = s_i + d^(i+1)*c.
    // sum y^2 = A + 2c*Bc + c^2*G16.
    float s = 0.f, A = 0.f, Bc = 0.f, w = 1.f;
    STEP(a0.x - b0.x) STEP(a0.y - b0.y) STEP(a0.z - b0.z) STEP(a0.w - b0.w)
    STEP(a1.x - b1.x) STEP(a1.y - b1.y) STEP(a1.z - b1.z) STEP(a1.w - b1.w)
    STEP(a2.x - b2.x) STEP(a2.y - b2.y) STEP(a2.z - b2.z) STEP(a2.w - b2.w)
    STEP(a3.x - b3.x) STEP(a3.y - b3.y) STEP(a3.z - b3.z) STEP(a3.w - b3.w)

    // ---- affine scan of carries: f_t(c) = a*c + b, compose low->high ----
    float a = D16_F;    // d^SEG
    float b = s;        // segment end value from zero carry
    const int lane = tid & 63;
    #pragma unroll
    for (int j = 1; j < 64; j <<= 1) {
        const float au = __shfl_up(a, j);
        const float bu = __shfl_up(b, j);
        if (lane >= j) {
            b = __builtin_fmaf(a, bu, b);       // self o lower
            a *= au;
        }
    }
    const int wid = tid >> 6;
    if (lane == 63) { wa[wid] = a; wb[wid] = b; }
    __syncthreads();

    // carry entering this wave (scan 0..wid-1 wave aggregates; LDS broadcast)
    float C = 0.f;
    for (int k = 0; k < wid; ++k) C = __builtin_fmaf(wa[k], C, wb[k]);
    // exclusive intra-wave aggregate
    float aex = __shfl_up(a, 1);
    float bex = __shfl_up(b, 1);
    if (lane == 0) { aex = 1.f; bex = 0.f; }
    const float c = __builtin_fmaf(aex, C, bex);   // carry into this thread

    float part = A + 2.f * c * Bc + (c * c) * G16_F;

    // ---- block reduce (deterministic) ----
    #pragma unroll
    for (int j = 32; j > 0; j >>= 1) part += __shfl_down(part, j);
    if (lane == 0) red[wid] = part;
    __syncthreads();
    if (tid == 0) {
        float t = 0.f;
        #pragma unroll
        for (int k = 0; k < NWAVES; ++k) t += red[k];
        // release the per-row partial to agent (device) scope, then count
        __hip_atomic_store(&partial[row], t, __ATOMIC_RELEASE,
                           __HIP_MEMORY_SCOPE_AGENT);
        const unsigned int old = __hip_atomic_fetch_add(
            counter, 1u, __ATOMIC_ACQ_REL, __HIP_MEMORY_SCOPE_AGENT);
        lastdone = (old == (unsigned int)(nrows - 1)) ? 1 : 0;
    }
    __syncthreads();

    // ---- last finishing block reduces all row partials (deterministic) ----
    if (lastdone) {
        float v = (tid < nrows)
            ? __hip_atomic_load(&partial[tid], __ATOMIC_RELAXED,
                                __HIP_MEMORY_SCOPE_AGENT)
            : 0.f;
        #pragma unroll
        for (int j = 32; j > 0; j >>= 1) v += __shfl_down(v, j);
        if (lane == 0) red[wid] = v;
        __syncthreads();
        if (tid == 0) {
            float t = 0.f;
            #pragma unroll
            for (int k = 0; k < NWAVES; ++k) t += red[k];
            out[0] = sqrtf(t * 0.05f);   // sqrt((1/TAU) * sum * DT)
        }
    }
}

extern "C" void kernel_launch(void* const* d_in, const int* in_sizes, int n_in,
                              void* d_out, int out_size, void* d_ws, size_t ws_size,
                              hipStream_t stream) {
    const float* in  = (const float*)d_in[0];
    const float* tgt = (const float*)d_in[1];
    float* out = (float*)d_out;
    float* partial = (float*)d_ws;                         // nrows floats
    const int rows = in_sizes[0] / LEN;                    // 1024
    unsigned int* counter = (unsigned int*)(partial + rows);

    // zero the completion counter each call (graph-capturable memset node)
    hipMemsetAsync(counter, 0, sizeof(unsigned int), stream);
    vr_fused<<<dim3(rows), dim3(NTHREADS), 0, stream>>>(
        in, tgt, partial, counter, out, rows);
}

// Round 4
// 74.260 us; speedup vs baseline: 1.0144x; 1.0144x over previous
//
#include <hip/hip_runtime.h>
#include <math.h>

#define LEN       16384
#define NTHREADS  1024
#define SEG       16          // LEN / NTHREADS
#define NWAVES    16

// exp(-1/20) and derived constants (double-precision values)
#define DECAY_F 0.951229424500714f      // d = exp(-0.05)
#define D16_F   0.449328964117222f      // d^16 = exp(-0.8)
#define G16_F   7.5886329f              // sum_{i=1..16} d^(2i)

// Full XOR swizzle (word granularity): conflict-free reads (2 lanes/bank),
// 2-way writes (free on CDNA4). Verified 0 SQ_LDS_BANK_CONFLICT in r1/r2.
__device__ __forceinline__ int swz(int a) { return a ^ ((a >> 5) & 31); }

// one scan step: s = d*s + x; A += s^2; Bc += d^(i+1)*s  (w constant-folds)
#define STEP(xv) { s = __builtin_fmaf(DECAY_F, s, (xv)); w *= DECAY_F; \
                   A = __builtin_fmaf(s, s, A); Bc = __builtin_fmaf(w, s, Bc); }

__global__ __launch_bounds__(NTHREADS) void vr_fused(
    const float* __restrict__ in, const float* __restrict__ tgt,
    float* __restrict__ partial, unsigned int* __restrict__ counter,
    float* __restrict__ out, int nrows)
{
    __shared__ float smem[LEN];                 // 64 KiB -> 2 blocks/CU
    __shared__ float wa[NWAVES], wb[NWAVES], red[NWAVES];
    __shared__ int lastdone;

    const int row = blockIdx.x;
    const int tid = threadIdx.x;
    const long long rb = (long long)row * LEN;
    const float4* __restrict__ in4 = (const float4*)(in  + rb);
    const float4* __restrict__ tg4 = (const float4*)(tgt + rb);

    // ---- phase 1a: issue ALL 8 independent coalesced float4 loads (MLP=8) ----
    const float4 a0 = in4[tid];
    const float4 a1 = in4[tid + NTHREADS];
    const float4 a2 = in4[tid + 2 * NTHREADS];
    const float4 a3 = in4[tid + 3 * NTHREADS];
    const float4 b0 = tg4[tid];
    const float4 b1 = tg4[tid + NTHREADS];
    const float4 b2 = tg4[tid + 2 * NTHREADS];
    const float4 b3 = tg4[tid + 3 * NTHREADS];

    // ---- phase 1b: diff -> swizzled LDS ----
    {
        int base = (tid) * 4;
        smem[swz(base + 0)] = a0.x - b0.x; smem[swz(base + 1)] = a0.y - b0.y;
        smem[swz(base + 2)] = a0.z - b0.z; smem[swz(base + 3)] = a0.w - b0.w;
        base = (tid + NTHREADS) * 4;
        smem[swz(base + 0)] = a1.x - b1.x; smem[swz(base + 1)] = a1.y - b1.y;
        smem[swz(base + 2)] = a1.z - b1.z; smem[swz(base + 3)] = a1.w - b1.w;
        base = (tid + 2 * NTHREADS) * 4;
        smem[swz(base + 0)] = a2.x - b2.x; smem[swz(base + 1)] = a2.y - b2.y;
        smem[swz(base + 2)] = a2.z - b2.z; smem[swz(base + 3)] = a2.w - b2.w;
        base = (tid + 3 * NTHREADS) * 4;
        smem[swz(base + 0)] = a3.x - b3.x; smem[swz(base + 1)] = a3.y - b3.y;
        smem[swz(base + 2)] = a3.z - b3.z; smem[swz(base + 3)] = a3.w - b3.w;
    }
    __syncthreads();

    // ---- phase 2: per-thread local scan + moments ----
    // s_i: local scan from 0.  True y_i = s_i + d^(i+1)*c (c = carry-in).
    // sum y^2 = A + 2c*Bc + c^2*G16.
    float s = 0.f, A = 0.f, Bc = 0.f, w = 1.f;
    const int base = tid * SEG;
    #pragma unroll
    for (int i = 0; i < SEG; ++i) {
        const float x = smem[swz(base + i)];
        STEP(x)
    }

    // ---- affine scan of carries: f_t(c) = a*c + b, compose low->high ----
    float a = D16_F;    // d^SEG
    float b = s;        // segment end value from zero carry
    const int lane = tid & 63;
    #pragma unroll
    for (int j = 1; j < 64; j <<= 1) {
        const float au = __shfl_up(a, j);
        const float bu = __shfl_up(b, j);
        if (lane >= j) {
            b = __builtin_fmaf(a, bu, b);       // self o lower
            a *= au;
        }
    }
    const int wid = tid >> 6;
    if (lane == 63) { wa[wid] = a; wb[wid] = b; }
    __syncthreads();

    // carry entering this wave (scan 0..wid-1 wave aggregates; LDS broadcast)
    float C = 0.f;
    for (int k = 0; k < wid; ++k) C = __builtin_fmaf(wa[k], C, wb[k]);
    // exclusive intra-wave aggregate
    float aex = __shfl_up(a, 1);
    float bex = __shfl_up(b, 1);
    if (lane == 0) { aex = 1.f; bex = 0.f; }
    const float c = __builtin_fmaf(aex, C, bex);   // carry into this thread

    float part = A + 2.f * c * Bc + (c * c) * G16_F;

    // ---- block reduce (deterministic) ----
    #pragma unroll
    for (int j = 32; j > 0; j >>= 1) part += __shfl_down(part, j);
    if (lane == 0) red[wid] = part;
    __syncthreads();
    if (tid == 0) {
        float t = 0.f;
        #pragma unroll
        for (int k = 0; k < NWAVES; ++k) t += red[k];
        // release per-row partial to agent (device) scope, then count
        __hip_atomic_store(&partial[row], t, __ATOMIC_RELEASE,
                           __HIP_MEMORY_SCOPE_AGENT);
        const unsigned int old = __hip_atomic_fetch_add(
            counter, 1u, __ATOMIC_ACQ_REL, __HIP_MEMORY_SCOPE_AGENT);
        lastdone = (old == (unsigned int)(nrows - 1)) ? 1 : 0;
    }
    __syncthreads();

    // ---- last finishing block reduces all row partials (deterministic) ----
    if (lastdone) {
        float v = (tid < nrows)
            ? __hip_atomic_load(&partial[tid], __ATOMIC_RELAXED,
                                __HIP_MEMORY_SCOPE_AGENT)
            : 0.f;
        #pragma unroll
        for (int j = 32; j > 0; j >>= 1) v += __shfl_down(v, j);
        if (lane == 0) red[wid] = v;
        __syncthreads();
        if (tid == 0) {
            float t = 0.f;
            #pragma unroll
            for (int k = 0; k < NWAVES; ++k) t += red[k];
            out[0] = sqrtf(t * 0.05f);   // sqrt((1/TAU) * sum * DT)
        }
    }
}

extern "C" void kernel_launch(void* const* d_in, const int* in_sizes, int n_in,
                              void* d_out, int out_size, void* d_ws, size_t ws_size,
                              hipStream_t stream) {
    const float* in  = (const float*)d_in[0];
    const float* tgt = (const float*)d_in[1];
    float* out = (float*)d_out;
    float* partial = (float*)d_ws;                         // nrows floats
    const int rows = in_sizes[0] / LEN;                    // 1024
    unsigned int* counter = (unsigned int*)(partial + rows);

    // zero the completion counter each call (graph-capturable memset node)
    hipMemsetAsync(counter, 0, sizeof(unsigned int), stream);
    vr_fused<<<dim3(rows), dim3(NTHREADS), 0, stream>>>(
        in, tgt, partial, counter, out, rows);
}

// Round 5
// 27.954 us; speedup vs baseline: 2.6948x; 2.6565x over previous
//
#include <hip/hip_runtime.h>
#include <math.h>

#define LEN       16384
#define NTHREADS  1024
#define SEG       16          // LEN / NTHREADS
#define NWAVES    16

// exp(-1/20) and derived constants (double-precision values)
#define DECAY_F 0.951229424500714f      // d = exp(-0.05)
#define D16_F   0.449328964117222f      // d^16 = exp(-0.8)
#define G16_F   7.5886329f              // sum_{i=1..16} d^(2i)

// Full XOR swizzle (word granularity): conflict-free reads (2 lanes/bank),
// 2-way writes (free on CDNA4). Verified 0 SQ_LDS_BANK_CONFLICT in r1/r2.
// XOR touches only bits 0..4 -> permutation stays within each 32-word group,
// hence within each wave's private 1024-word chunk (wave-sync safe).
__device__ __forceinline__ int swz(int a) { return a ^ ((a >> 5) & 31); }

// one scan step: s = d*s + x; A += s^2; Bc += d^(i+1)*s  (w constant-folds)
#define STEP(xv) { s = __builtin_fmaf(DECAY_F, s, (xv)); ww *= DECAY_F; \
                   A = __builtin_fmaf(s, s, A); Bc = __builtin_fmaf(ww, s, Bc); }

__global__ __launch_bounds__(NTHREADS) void vr_main(
    const float* __restrict__ in, const float* __restrict__ tgt,
    float* __restrict__ partial)
{
    __shared__ float smem[LEN];                 // 64 KiB -> 2 blocks/CU
    __shared__ float wa[NWAVES], wb[NWAVES], red[NWAVES];

    const int tid  = threadIdx.x;
    const int lane = tid & 63;
    const int wid  = tid >> 6;
    const long long rb = (long long)blockIdx.x * LEN;
    const float4* __restrict__ in4 = (const float4*)(in  + rb);
    const float4* __restrict__ tg4 = (const float4*)(tgt + rb);

    // Wave-private chunk: wave w owns words [1024w, 1024w+1024).
    // float4 index base for this lane within the chunk:
    const int cb4 = (wid << 8) + lane;          // 256*wid + lane

    // ---- phase 1a: 8 independent coalesced float4 loads, pinned live ----
    const float4 a0 = in4[cb4];       const float4 b0 = tg4[cb4];
    const float4 a1 = in4[cb4 +  64]; const float4 b1 = tg4[cb4 +  64];
    const float4 a2 = in4[cb4 + 128]; const float4 b2 = tg4[cb4 + 128];
    const float4 a3 = in4[cb4 + 192]; const float4 b3 = tg4[cb4 + 192];
    __builtin_amdgcn_sched_barrier(0);          // loads may not sink below

    // ---- phase 1b: diff -> swizzled LDS (stays inside own wave chunk) ----
    {
        int base = cb4 * 4;
        smem[swz(base + 0)] = a0.x - b0.x; smem[swz(base + 1)] = a0.y - b0.y;
        smem[swz(base + 2)] = a0.z - b0.z; smem[swz(base + 3)] = a0.w - b0.w;
        base = (cb4 + 64) * 4;
        smem[swz(base + 0)] = a1.x - b1.x; smem[swz(base + 1)] = a1.y - b1.y;
        smem[swz(base + 2)] = a1.z - b1.z; smem[swz(base + 3)] = a1.w - b1.w;
        base = (cb4 + 128) * 4;
        smem[swz(base + 0)] = a2.x - b2.x; smem[swz(base + 1)] = a2.y - b2.y;
        smem[swz(base + 2)] = a2.z - b2.z; smem[swz(base + 3)] = a2.w - b2.w;
        base = (cb4 + 192) * 4;
        smem[swz(base + 0)] = a3.x - b3.x; smem[swz(base + 1)] = a3.y - b3.y;
        smem[swz(base + 2)] = a3.z - b3.z; smem[swz(base + 3)] = a3.w - b3.w;
    }
    // Wave-local sync: this wave's ds_writes retired before its ds_reads.
    // (No __syncthreads needed: producer lanes == consumer lanes' wave.)
    asm volatile("s_waitcnt lgkmcnt(0)" ::: "memory");
    __builtin_amdgcn_sched_barrier(0);

    // ---- phase 2: per-thread local scan + moments (segment = tid) ----
    // s_i: local scan from 0.  True y_i = s_i + d^(i+1)*c (c = carry-in).
    // sum y^2 = A + 2c*Bc + c^2*G16.
    float s = 0.f, A = 0.f, Bc = 0.f, ww = 1.f;
    const int base = tid * SEG;
    #pragma unroll
    for (int i = 0; i < SEG; ++i) {
        const float x = smem[swz(base + i)];
        STEP(x)
    }

    // ---- affine scan of carries: f_t(c) = a*c + b, compose low->high ----
    float a = D16_F;    // d^SEG
    float b = s;        // segment end value from zero carry
    #pragma unroll
    for (int j = 1; j < 64; j <<= 1) {
        const float au = __shfl_up(a, j);
        const float bu = __shfl_up(b, j);
        if (lane >= j) {
            b = __builtin_fmaf(a, bu, b);       // self o lower
            a *= au;
        }
    }
    if (lane == 63) { wa[wid] = a; wb[wid] = b; }
    __syncthreads();

    // carry entering this wave (scan 0..wid-1 wave aggregates; LDS broadcast)
    float C = 0.f;
    for (int k = 0; k < wid; ++k) C = __builtin_fmaf(wa[k], C, wb[k]);
    // exclusive intra-wave aggregate
    float aex = __shfl_up(a, 1);
    float bex = __shfl_up(b, 1);
    if (lane == 0) { aex = 1.f; bex = 0.f; }
    const float c = __builtin_fmaf(aex, C, bex);   // carry into this thread

    float part = A + 2.f * c * Bc + (c * c) * G16_F;

    // ---- block reduce (deterministic), write per-row partial ----
    #pragma unroll
    for (int j = 32; j > 0; j >>= 1) part += __shfl_down(part, j);
    if (lane == 0) red[wid] = part;
    __syncthreads();
    if (tid == 0) {
        float t = 0.f;
        #pragma unroll
        for (int k = 0; k < NWAVES; ++k) t += red[k];
        partial[blockIdx.x] = t;
    }
}

__global__ __launch_bounds__(1024) void vr_final(
    const float* __restrict__ partial, int n, float* __restrict__ out)
{
    __shared__ float red[16];
    const int tid = threadIdx.x;
    float v = 0.f;
    for (int k = tid; k < n; k += 1024) v += partial[k];
    #pragma unroll
    for (int j = 32; j > 0; j >>= 1) v += __shfl_down(v, j);
    const int lane = tid & 63, wid = tid >> 6;
    if (lane == 0) red[wid] = v;
    __syncthreads();
    if (tid == 0) {
        float t = 0.f;
        #pragma unroll
        for (int k = 0; k < 16; ++k) t += red[k];
        out[0] = sqrtf(t * 0.05f);   // sqrt((1/TAU) * sum * DT)
    }
}

extern "C" void kernel_launch(void* const* d_in, const int* in_sizes, int n_in,
                              void* d_out, int out_size, void* d_ws, size_t ws_size,
                              hipStream_t stream) {
    const float* in  = (const float*)d_in[0];
    const float* tgt = (const float*)d_in[1];
    float* out = (float*)d_out;
    float* ws  = (float*)d_ws;          // rows floats of scratch (4 KiB)
    const int rows = in_sizes[0] / LEN; // 1024

    vr_main<<<dim3(rows), dim3(NTHREADS), 0, stream>>>(in, tgt, ws);
    vr_final<<<dim3(1), dim3(1024), 0, stream>>>(ws, rows, out);
}